// Round 3
// baseline (12180.413 us; speedup 1.0000x reference)
//
#include <hip/hip_runtime.h>
#include <cstdint>
#include <cstddef>

// ---------------- problem constants ----------------
#define T_STEPS 2048
#define NBATCH  64
#define HID     256
#define NGATE   1024            // 4*HID

// recurrent kernel: 8 waves, wave wv owns units [wv*32, wv*32+32)
// col-tiles per wave t8=0..7: gate g=t8>>1, half hf=t8&1, col0 = g*256+wv*32+hf*16
// K=256 -> 8 K-tiles of 32; kt 0..5 register-resident, kt 6..7 in LDS
#define REC_LDS_BYTES (128*1024 + 1024)     // 128 KB weight tail + 2 x 256 f16 h buffers

typedef _Float16 f16x8 __attribute__((ext_vector_type(8)));
typedef float    f32x4 __attribute__((ext_vector_type(4)));
typedef unsigned short u16x4 __attribute__((ext_vector_type(4)));

__device__ __forceinline__ unsigned short f2h_bits(float f) {
    _Float16 h = (_Float16)f;
    return __builtin_bit_cast(unsigned short, h);
}
__device__ __forceinline__ float h2f_scalar(unsigned short u) {
    return (float)__builtin_bit_cast(_Float16, u);
}

// ---------------- workspace layout (bytes) ----------------
#define OFF_G    ((size_t)0)                    // 131072*1024 fp16 = 268435456 (aliased G0/G1)
#define OFF_Y0   ((size_t)268435456)            // 2048*64*256 fp16 = 67108864
#define OFF_RW0  ((size_t)335544320)            // 8*8*6*64*8 f16 = 393216 B (reg frags)
#define OFF_RW1  ((size_t)335937536)
#define OFF_LF0  ((size_t)336330752)            // 8*8*2*64*8 f16 = 131072 B (LDS tail frags)
#define OFF_LF1  ((size_t)336461824)
#define OFF_BS0  ((size_t)336592896)            // 128*1024 fp16 swizzled = 262144 B
#define OFF_BS1  ((size_t)336855040)            // 256*1024 fp16 swizzled = 524288 B
#define WS_NEED  ((size_t)337379328)

// ---------------- weight conversion / swizzle ----------------
// MFMA fragment layouts (same mapping the working gemm_in uses):
//   B-frag: lane l element i  <->  W[k = kt*32 + (l>>4)*8 + i][col = col0 + (l&15)]
__global__ void convert_weights(const float* __restrict__ w_ih0, const float* __restrict__ w_hh0,
                                const float* __restrict__ w_ih1, const float* __restrict__ w_hh1,
                                unsigned short* __restrict__ RW0, unsigned short* __restrict__ RW1,
                                unsigned short* __restrict__ LF0, unsigned short* __restrict__ LF1,
                                unsigned short* __restrict__ BS0, unsigned short* __restrict__ BS1)
{
    int gid = blockIdx.x * blockDim.x + threadIdx.x;
    int gsz = gridDim.x * blockDim.x;
    // RW: s = (((wv*8 + t8)*6 + kt)*64 + l)*8 + i   (196608 per layer)
    for (int s = gid; s < 196608; s += gsz) {
        int i = s & 7, l = (s >> 3) & 63;
        int rest = s >> 9;
        int kt = rest % 6, m2 = rest / 6;
        int t8 = m2 & 7, wv = m2 >> 3;
        int col0 = (t8 >> 1) * 256 + wv * 32 + (t8 & 1) * 16;
        int k = kt * 32 + (l >> 4) * 8 + i;
        int col = col0 + (l & 15);
        RW0[s] = f2h_bits(w_hh0[k * 1024 + col]);
        RW1[s] = f2h_bits(w_hh1[k * 1024 + col]);
    }
    // LF: s = (((wv*8 + t8)*2 + kc)*64 + l)*8 + i   (65536 per layer), kt = 6+kc
    for (int s = gid; s < 65536; s += gsz) {
        int i = s & 7, l = (s >> 3) & 63;
        int rest = s >> 9;
        int kc = rest & 1, t8 = (rest >> 1) & 7, wv = rest >> 4;
        int col0 = (t8 >> 1) * 256 + wv * 32 + (t8 & 1) * 16;
        int k = (6 + kc) * 32 + (l >> 4) * 8 + i;
        int col = col0 + (l & 15);
        LF0[s] = f2h_bits(w_hh0[k * 1024 + col]);
        LF1[s] = f2h_bits(w_hh1[k * 1024 + col]);
    }
    // Bswz layer0: K=128 (KB=4): s = ((n16*KB+kb)*64+lane)*8+i
    for (int s = gid; s < 131072; s += gsz) {
        int i = s & 7, lane = (s >> 3) & 63, kb = (s >> 9) & 3, n16 = s >> 11;
        int k = kb * 32 + (lane >> 4) * 8 + i;
        int n = n16 * 16 + (lane & 15);
        BS0[s] = f2h_bits(w_ih0[k * 1024 + n]);
    }
    // Bswz layer1: K=256 (KB=8)
    for (int s = gid; s < 262144; s += gsz) {
        int i = s & 7, lane = (s >> 3) & 63, kb = (s >> 9) & 7, n16 = s >> 12;
        int k = kb * 32 + (lane >> 4) * 8 + i;
        int n = n16 * 16 + (lane & 15);
        BS1[s] = f2h_bits(w_ih1[k * 1024 + n]);
    }
}

// ---------------- input-gate GEMM: G[r][swz(n)] = A[map(r)][:] @ w_ih[:, n] + b[n] ----------------
// r = t*64 + b ; layer0: A = x fp32, row (b*2048 + 2047-t), K=128
//                layer1: A = y0 fp16, row ((2047-t)*64 + b), K=256
// G is stored gate-interleaved: col (gate*256+m) -> m*4+gate so the recurrent
// kernel reads all 4 of a unit's gate values with ONE b64 load.
template <int KB, int LAYER>
__global__ __launch_bounds__(256) void gemm_in(const float* __restrict__ A32,
                                               const unsigned short* __restrict__ A16,
                                               const unsigned short* __restrict__ Bsw,
                                               const float* __restrict__ bias,
                                               unsigned short* __restrict__ Gout)
{
    const int lane = threadIdx.x & 63;
    const int wave = threadIdx.x >> 6;
    const int nblk = blockIdx.x & 15;        // 16 n-blocks of 64 cols
    const int rblk = blockIdx.x >> 4;        // 1024 r-blocks of 128 rows
    const int r0 = rblk * 128 + wave * 32;
    const int quad = lane >> 4, ln = lane & 15;

    f32x4 acc[2][4];
#pragma unroll
    for (int q = 0; q < 4; q++) {
        float bv = bias[(nblk * 4 + q) * 16 + ln];
#pragma unroll
        for (int mt = 0; mt < 2; mt++) {
            acc[mt][q][0] = bv; acc[mt][q][1] = bv; acc[mt][q][2] = bv; acc[mt][q][3] = bv;
        }
    }
    const int ar0 = r0 + ln, ar1 = r0 + 16 + ln;
    size_t aoff0, aoff1;
    if (LAYER == 0) {
        aoff0 = ((size_t)(ar0 & 63) * 2048 + (size_t)(2047 - (ar0 >> 6))) * 128;
        aoff1 = ((size_t)(ar1 & 63) * 2048 + (size_t)(2047 - (ar1 >> 6))) * 128;
    } else {
        aoff0 = ((size_t)(2047 - (ar0 >> 6)) * 64 + (size_t)(ar0 & 63)) * 256;
        aoff1 = ((size_t)(2047 - (ar1 >> 6)) * 64 + (size_t)(ar1 & 63)) * 256;
    }
#pragma unroll
    for (int kb = 0; kb < KB; kb++) {
        const int k0 = kb * 32 + quad * 8;
        f16x8 a0, a1;
        if (LAYER == 0) {
            const float* p0 = A32 + aoff0 + k0;
            const float* p1 = A32 + aoff1 + k0;
            float4 fa = *(const float4*)(p0);
            float4 fb = *(const float4*)(p0 + 4);
            float4 fc = *(const float4*)(p1);
            float4 fd = *(const float4*)(p1 + 4);
            a0[0] = (_Float16)fa.x; a0[1] = (_Float16)fa.y; a0[2] = (_Float16)fa.z; a0[3] = (_Float16)fa.w;
            a0[4] = (_Float16)fb.x; a0[5] = (_Float16)fb.y; a0[6] = (_Float16)fb.z; a0[7] = (_Float16)fb.w;
            a1[0] = (_Float16)fc.x; a1[1] = (_Float16)fc.y; a1[2] = (_Float16)fc.z; a1[3] = (_Float16)fc.w;
            a1[4] = (_Float16)fd.x; a1[5] = (_Float16)fd.y; a1[6] = (_Float16)fd.z; a1[7] = (_Float16)fd.w;
        } else {
            a0 = *(const f16x8*)(A16 + aoff0 + k0);
            a1 = *(const f16x8*)(A16 + aoff1 + k0);
        }
#pragma unroll
        for (int q = 0; q < 4; q++) {
            f16x8 bq = *(const f16x8*)(Bsw + (((size_t)(nblk * 4 + q) * KB + kb) * 64 + lane) * 8);
            acc[0][q] = __builtin_amdgcn_mfma_f32_16x16x32_f16(a0, bq, acc[0][q], 0, 0, 0);
            acc[1][q] = __builtin_amdgcn_mfma_f32_16x16x32_f16(a1, bq, acc[1][q], 0, 0, 0);
        }
    }
    // C/D layout: col = lane&15, row = (lane>>4)*4 + reg.  Store gate-interleaved.
#pragma unroll
    for (int mt = 0; mt < 2; mt++)
#pragma unroll
        for (int q = 0; q < 4; q++)
#pragma unroll
            for (int rg = 0; rg < 4; rg++) {
                int row = r0 + mt * 16 + quad * 4 + rg;
                int col = (nblk * 4 + q) * 16 + ln;
                int swz = ((col & 255) << 2) | (col >> 8);
                Gout[(size_t)row * 1024 + swz] = f2h_bits(acc[mt][q][rg]);
            }
}

// ---------------- persistent recurrent kernel: 1 WG per batch element ----------------
// MFMA formulation. 512 threads, 8 waves; wave wv owns units [wv*32, wv*32+32).
// A-operand = h replicated into all 16 M-rows (lane l reads h k-chunk (l>>4)*8,
// independent of l&15) -> all C rows equal -> every lane holds gates[col=l&15]
// of each of its 8 col-tiles; epilogue is fully lane-local (2 units per lane,
// redundant across the 4 quads; quad 0 does the stores).
// Weights: kt 0..5 in registers (48 f16x8 frags = 192 VGPRs), kt 6..7 in LDS
// (128 KB, read once per step). Accumulation in 2 passes of 4 col-tiles to
// stay under the 256-VGPR/wave cap at 2 waves/SIMD.
template <int LAYER>
__global__ __launch_bounds__(512, 2) void lstm_rec(const unsigned short* __restrict__ G,
                                                   const unsigned short* __restrict__ RW,
                                                   const unsigned short* __restrict__ LF,
                                                   unsigned short* __restrict__ Y0,
                                                   float* __restrict__ Out)
{
    extern __shared__ char smem[];
    unsigned short* lds_w  = (unsigned short*)smem;                 // 65536 f16 = 8192 uint4
    unsigned short* lds_h0 = (unsigned short*)(smem + 128 * 1024);  // 256 f16
    unsigned short* lds_h1 = lds_h0 + 256;                          // 256 f16

    const int b = blockIdx.x;
    const int tid = threadIdx.x;
    const int wv = tid >> 6, l = tid & 63;
    const int q = l >> 4, ln = l & 15;
    const int u_low = wv * 32 + ln;
    const int u_high = u_low + 16;

    // register-resident weight fragments: rw[t8][kt], kt = 0..5
    f16x8 rw[8][6];
#pragma unroll
    for (int t8 = 0; t8 < 8; ++t8)
#pragma unroll
        for (int kt = 0; kt < 6; ++kt)
            rw[t8][kt] = *(const f16x8*)(RW + (((size_t)(wv * 8 + t8) * 6 + kt) * 64 + l) * 8);

    // stage LDS-resident weight tail (kt = 6,7)
    {
        const uint4* src = (const uint4*)LF;
        uint4* dst = (uint4*)lds_w;
        for (int i = tid; i < 8192; i += 512) dst[i] = src[i];
    }
    if (tid < 256) lds_h0[tid] = 0;
    float c_l = 0.f, c_h = 0.f, hp_l = 0.f, hp_h = 0.f;
    __syncthreads();

    // G: gate-interleaved rows r = t*64 + b; as u16x4: element (r*256 + u) = 4 gates of unit u
    const u16x4* Gp = (const u16x4*)G;
    const size_t gbl = (size_t)b * 256 + u_low;
    const size_t gbh = gbl + 16;
    u16x4 gl = Gp[gbl];            // t = 0
    u16x4 gh = Gp[gbh];

    for (int t = 0; t < T_STEPS; ++t) {
        // prefetch next step's G (full-step latency cover)
        const int tn = (t + 1 < T_STEPS) ? t + 1 : t;
        u16x4 gln = Gp[(size_t)tn * 16384 + gbl];
        u16x4 ghn = Gp[(size_t)tn * 16384 + gbh];
        // deferred store of h_{t-1}: retires during the mfma phase
        if (t && q == 0) {
            if (LAYER == 0) {
                Y0[((size_t)(t - 1) * 64 + b) * 256 + u_low]  = f2h_bits(hp_l);
                Y0[((size_t)(t - 1) * 64 + b) * 256 + u_high] = f2h_bits(hp_h);
            } else {
                Out[((size_t)(t - 1) * 64 + b) * 256 + u_low]  = hp_l;
                Out[((size_t)(t - 1) * 64 + b) * 256 + u_high] = hp_h;
            }
        }
        const unsigned short* hbuf = (t & 1) ? lds_h1 : lds_h0;

        float svf_l, svf_h, svi_l, svi_h;
        float so_l, so_h, sg_l, sg_h;
#pragma unroll
        for (int p = 0; p < 2; ++p) {
            f32x4 acc[4];
#pragma unroll
            for (int j = 0; j < 4; ++j) {
                // tile t8 = p*4+j: gate = p*2 + (j>>1); from gl if j even else gh
                unsigned short gv = (j & 1) ? gh[p * 2 + (j >> 1)] : gl[p * 2 + (j >> 1)];
                acc[j][0] = h2f_scalar(gv);
                acc[j][1] = 0.f; acc[j][2] = 0.f; acc[j][3] = 0.f;
            }
#pragma unroll
            for (int kt = 0; kt < 8; ++kt) {
                f16x8 av = *(const f16x8*)(hbuf + kt * 32 + q * 8);   // 16-lane broadcast groups
#pragma unroll
                for (int j = 0; j < 4; ++j) {
                    const int t8 = p * 4 + j;
                    f16x8 bv;
                    if (kt < 6) {
                        bv = rw[t8][kt];
                    } else {
                        bv = *(const f16x8*)(lds_w + (((size_t)(wv * 8 + t8) * 2 + (kt - 6)) * 64 + l) * 8);
                    }
                    acc[j] = __builtin_amdgcn_mfma_f32_16x16x32_f16(av, bv, acc[j], 0, 0, 0);
                }
            }
            if (p == 0) {
                svf_l = acc[0][0]; svf_h = acc[1][0];
                svi_l = acc[2][0]; svi_h = acc[3][0];
            } else {
                so_l = acc[0][0]; so_h = acc[1][0];
                sg_l = acc[2][0]; sg_h = acc[3][0];
            }
        }
        // epilogue (lane-local; redundant across quads)
        {
            float sf = 1.f / (1.f + __expf(-svf_l));
            float si = 1.f / (1.f + __expf(-svi_l));
            float so = 1.f / (1.f + __expf(-so_l));
            float tg = 1.f - 2.f / (1.f + __expf(2.f * sg_l));
            c_l = sf * c_l + si * tg;
            float tc = 1.f - 2.f / (1.f + __expf(2.f * c_l));
            hp_l = so * tc;
        }
        {
            float sf = 1.f / (1.f + __expf(-svf_h));
            float si = 1.f / (1.f + __expf(-svi_h));
            float so = 1.f / (1.f + __expf(-so_h));
            float tg = 1.f - 2.f / (1.f + __expf(2.f * sg_h));
            c_h = sf * c_h + si * tg;
            float tc = 1.f - 2.f / (1.f + __expf(2.f * c_h));
            hp_h = so * tc;
        }
        unsigned short* hn = (t & 1) ? lds_h0 : lds_h1;
        if (q == 0) {
            hn[u_low]  = f2h_bits(hp_l);
            hn[u_high] = f2h_bits(hp_h);
        }
        gl = gln; gh = ghn;
        __syncthreads();
    }
    if (q == 0) {
        if (LAYER == 0) {
            Y0[((size_t)(T_STEPS - 1) * 64 + b) * 256 + u_low]  = f2h_bits(hp_l);
            Y0[((size_t)(T_STEPS - 1) * 64 + b) * 256 + u_high] = f2h_bits(hp_h);
        } else {
            Out[((size_t)(T_STEPS - 1) * 64 + b) * 256 + u_low]  = hp_l;
            Out[((size_t)(T_STEPS - 1) * 64 + b) * 256 + u_high] = hp_h;
        }
        Out[(size_t)33554432 + (size_t)LAYER * 16384 + (size_t)b * 256 + u_low]  = hp_l;          // hn
        Out[(size_t)33554432 + (size_t)LAYER * 16384 + (size_t)b * 256 + u_high] = hp_h;
        Out[(size_t)33554432 + 32768 + (size_t)LAYER * 16384 + (size_t)b * 256 + u_low]  = c_l;   // cn
        Out[(size_t)33554432 + 32768 + (size_t)LAYER * 16384 + (size_t)b * 256 + u_high] = c_h;
    }
}

// ---------------- launch ----------------
extern "C" void kernel_launch(void* const* d_in, const int* in_sizes, int n_in,
                              void* d_out, int out_size, void* d_ws, size_t ws_size,
                              hipStream_t stream)
{
    const float* x     = (const float*)d_in[0];
    const float* w_ih0 = (const float*)d_in[1];
    const float* w_hh0 = (const float*)d_in[2];
    const float* b0    = (const float*)d_in[3];
    const float* w_ih1 = (const float*)d_in[4];
    const float* w_hh1 = (const float*)d_in[5];
    const float* b1    = (const float*)d_in[6];
    float* out = (float*)d_out;

    if (ws_size < WS_NEED) return;  // cannot run correctly; fail loudly (output stays poisoned)

    char* ws = (char*)d_ws;
    unsigned short* G   = (unsigned short*)(ws + OFF_G);
    unsigned short* Y0  = (unsigned short*)(ws + OFF_Y0);
    unsigned short* RW0 = (unsigned short*)(ws + OFF_RW0);
    unsigned short* RW1 = (unsigned short*)(ws + OFF_RW1);
    unsigned short* LF0 = (unsigned short*)(ws + OFF_LF0);
    unsigned short* LF1 = (unsigned short*)(ws + OFF_LF1);
    unsigned short* BS0 = (unsigned short*)(ws + OFF_BS0);
    unsigned short* BS1 = (unsigned short*)(ws + OFF_BS1);

    (void)hipFuncSetAttribute(reinterpret_cast<const void*>(&lstm_rec<0>),
                              hipFuncAttributeMaxDynamicSharedMemorySize, REC_LDS_BYTES);
    (void)hipFuncSetAttribute(reinterpret_cast<const void*>(&lstm_rec<1>),
                              hipFuncAttributeMaxDynamicSharedMemorySize, REC_LDS_BYTES);

    convert_weights<<<1024, 256, 0, stream>>>(w_ih0, w_hh0, w_ih1, w_hh1,
                                              RW0, RW1, LF0, LF1, BS0, BS1);
    gemm_in<4, 0><<<16384, 256, 0, stream>>>(x, nullptr, BS0, b0, G);
    lstm_rec<0><<<64, 512, REC_LDS_BYTES, stream>>>(G, RW0, LF0, Y0, out);
    gemm_in<8, 1><<<16384, 256, 0, stream>>>(nullptr, Y0, BS1, b1, G);
    lstm_rec<1><<<64, 512, REC_LDS_BYTES, stream>>>(G, RW1, LF1, Y0, out);
}

// Round 5
// 7956.823 us; speedup vs baseline: 1.5308x; 1.5308x over previous
//
#include <hip/hip_runtime.h>
#include <cstdint>
#include <cstddef>

// ---------------- problem constants ----------------
#define T_STEPS 2048
#define NBATCH  64
#define HID     256
#define NGATE   1024            // 4*HID

// recurrent kernel: 512 threads, 8 waves.
// wave wv: K-half kh = wv&1, unit group ug = wv>>1; lane l owns unit m = ug*64+l
// (all 4 gates f,i,o,g of unit m over k in [kh*128, kh*128+128)).
// Weights per lane: 4 gates x 64 u32 pairs = 256 u32 -> 48 uint4 in regs (jp 0..47),
// 16 uint4 in LDS (jp 48..63).
// h lives in SGPRs: 1 ds_read_b128 + 64 v_readlane per wave per step.
// K-half partials combined via 8KB LDS buffer (wave pair wv ^ 1), 2 barriers/step.
#define REC_LDS_BYTES (128*1024 + 8192 + 1024)   // tail 128KB + partials 8KB + 2x256 f16 h

typedef _Float16 f16x8 __attribute__((ext_vector_type(8)));
typedef _Float16 h2f   __attribute__((ext_vector_type(2)));
typedef float    f32x4 __attribute__((ext_vector_type(4)));
typedef unsigned short u16x4 __attribute__((ext_vector_type(4)));

__device__ __forceinline__ unsigned short f2h_bits(float f) {
    _Float16 h = (_Float16)f;
    return __builtin_bit_cast(unsigned short, h);
}
__device__ __forceinline__ float h2f_scalar(unsigned short u) {
    return (float)__builtin_bit_cast(_Float16, u);
}

// fdot2: acc += a.x*b.x + a.y*b.y  (f32 accumulate, v_dot2_f32_f16, full rate)
__device__ __forceinline__ float fdot2u(unsigned int hh, unsigned int ww, float acc) {
#if __has_builtin(__builtin_amdgcn_fdot2)
    return __builtin_amdgcn_fdot2(__builtin_bit_cast(h2f, hh),
                                  __builtin_bit_cast(h2f, ww), acc, false);
#else
    h2f a = __builtin_bit_cast(h2f, hh), b = __builtin_bit_cast(h2f, ww);
    return acc + (float)a.x * (float)b.x + (float)a.y * (float)b.y;
#endif
}

// ---------------- workspace layout (bytes) ----------------
#define OFF_G    ((size_t)0)                    // 131072*1024 fp16 = 268435456 (aliased G0/G1)
#define OFF_Y0   ((size_t)268435456)            // 2048*64*256 fp16 = 67108864
#define OFF_RW0  ((size_t)335544320)            // 48*512*8 f16 = 393216 B (reg weight frags)
#define OFF_RW1  ((size_t)335937536)
#define OFF_LF0  ((size_t)336330752)            // 16*512*8 f16 = 131072 B (LDS tail frags)
#define OFF_LF1  ((size_t)336461824)
#define OFF_BS0  ((size_t)336592896)            // 128*1024 fp16 swizzled = 262144 B
#define OFF_BS1  ((size_t)336855040)            // 256*1024 fp16 swizzled = 524288 B
#define WS_NEED  ((size_t)337379328)

// ---------------- weight conversion / swizzle ----------------
// Recurrent weight packing (lane slot = wv*64 + l, kh = wv&1, ug = wv>>1):
//   RW[(q*512 + slot)*8 + i], q = g*12 + c (c 0..11):
//       jp = c*4 + (i>>1); k = kh*128 + jp*2 + (i&1); col = g*256 + ug*64 + l
//   LF[(r*512 + slot)*8 + i], r = g*4 + cc (cc 0..3):
//       jp = 48 + cc*4 + (i>>1); k = kh*128 + jp*2 + (i&1); col = g*256 + ug*64 + l
__global__ void convert_weights(const float* __restrict__ w_ih0, const float* __restrict__ w_hh0,
                                const float* __restrict__ w_ih1, const float* __restrict__ w_hh1,
                                unsigned short* __restrict__ RW0, unsigned short* __restrict__ RW1,
                                unsigned short* __restrict__ LF0, unsigned short* __restrict__ LF1,
                                unsigned short* __restrict__ BS0, unsigned short* __restrict__ BS1)
{
    int gid = blockIdx.x * blockDim.x + threadIdx.x;
    int gsz = gridDim.x * blockDim.x;
    // RW: 48*512*8 = 196608 u16 per layer
    for (int s = gid; s < 196608; s += gsz) {
        int i = s & 7;
        int t = s >> 3;
        int slot = t & 511;
        int q = t >> 9;                 // 0..47
        int g = q / 12, c = q % 12;
        int l = slot & 63, wv = slot >> 6;
        int kh = wv & 1, ug = wv >> 1;
        int jp = c * 4 + (i >> 1);
        int k = kh * 128 + jp * 2 + (i & 1);
        int col = g * 256 + ug * 64 + l;
        RW0[s] = f2h_bits(w_hh0[k * 1024 + col]);
        RW1[s] = f2h_bits(w_hh1[k * 1024 + col]);
    }
    // LF: 16*512*8 = 65536 u16 per layer
    for (int s = gid; s < 65536; s += gsz) {
        int i = s & 7;
        int t = s >> 3;
        int slot = t & 511;
        int r = t >> 9;                 // 0..15
        int g = r >> 2, cc = r & 3;
        int l = slot & 63, wv = slot >> 6;
        int kh = wv & 1, ug = wv >> 1;
        int jp = 48 + cc * 4 + (i >> 1);
        int k = kh * 128 + jp * 2 + (i & 1);
        int col = g * 256 + ug * 64 + l;
        LF0[s] = f2h_bits(w_hh0[k * 1024 + col]);
        LF1[s] = f2h_bits(w_hh1[k * 1024 + col]);
    }
    // Bswz layer0: K=128 (KB=4): s = ((n16*KB+kb)*64+lane)*8+i
    for (int s = gid; s < 131072; s += gsz) {
        int i = s & 7, lane = (s >> 3) & 63, kb = (s >> 9) & 3, n16 = s >> 11;
        int k = kb * 32 + (lane >> 4) * 8 + i;
        int n = n16 * 16 + (lane & 15);
        BS0[s] = f2h_bits(w_ih0[k * 1024 + n]);
    }
    // Bswz layer1: K=256 (KB=8)
    for (int s = gid; s < 262144; s += gsz) {
        int i = s & 7, lane = (s >> 3) & 63, kb = (s >> 9) & 7, n16 = s >> 12;
        int k = kb * 32 + (lane >> 4) * 8 + i;
        int n = n16 * 16 + (lane & 15);
        BS1[s] = f2h_bits(w_ih1[k * 1024 + n]);
    }
}

// ---------------- input-gate GEMM: G[r][swz(n)] = A[map(r)][:] @ w_ih[:, n] + b[n] ----------------
// r = t*64 + b ; layer0: A = x fp32, row (b*2048 + 2047-t), K=128
//                layer1: A = y0 fp16, row ((2047-t)*64 + b), K=256
// G is stored gate-interleaved: col (gate*256+m) -> m*4+gate so the recurrent
// kernel reads all 4 of a unit's gate values with ONE b64 load.
template <int KB, int LAYER>
__global__ __launch_bounds__(256) void gemm_in(const float* __restrict__ A32,
                                               const unsigned short* __restrict__ A16,
                                               const unsigned short* __restrict__ Bsw,
                                               const float* __restrict__ bias,
                                               unsigned short* __restrict__ Gout)
{
    const int lane = threadIdx.x & 63;
    const int wave = threadIdx.x >> 6;
    const int nblk = blockIdx.x & 15;        // 16 n-blocks of 64 cols
    const int rblk = blockIdx.x >> 4;        // 1024 r-blocks of 128 rows
    const int r0 = rblk * 128 + wave * 32;
    const int quad = lane >> 4, ln = lane & 15;

    f32x4 acc[2][4];
#pragma unroll
    for (int q = 0; q < 4; q++) {
        float bv = bias[(nblk * 4 + q) * 16 + ln];
#pragma unroll
        for (int mt = 0; mt < 2; mt++) {
            acc[mt][q][0] = bv; acc[mt][q][1] = bv; acc[mt][q][2] = bv; acc[mt][q][3] = bv;
        }
    }
    const int ar0 = r0 + ln, ar1 = r0 + 16 + ln;
    size_t aoff0, aoff1;
    if (LAYER == 0) {
        aoff0 = ((size_t)(ar0 & 63) * 2048 + (size_t)(2047 - (ar0 >> 6))) * 128;
        aoff1 = ((size_t)(ar1 & 63) * 2048 + (size_t)(2047 - (ar1 >> 6))) * 128;
    } else {
        aoff0 = ((size_t)(2047 - (ar0 >> 6)) * 64 + (size_t)(ar0 & 63)) * 256;
        aoff1 = ((size_t)(2047 - (ar1 >> 6)) * 64 + (size_t)(ar1 & 63)) * 256;
    }
#pragma unroll
    for (int kb = 0; kb < KB; kb++) {
        const int k0 = kb * 32 + quad * 8;
        f16x8 a0, a1;
        if (LAYER == 0) {
            const float* p0 = A32 + aoff0 + k0;
            const float* p1 = A32 + aoff1 + k0;
            float4 fa = *(const float4*)(p0);
            float4 fb = *(const float4*)(p0 + 4);
            float4 fc = *(const float4*)(p1);
            float4 fd = *(const float4*)(p1 + 4);
            a0[0] = (_Float16)fa.x; a0[1] = (_Float16)fa.y; a0[2] = (_Float16)fa.z; a0[3] = (_Float16)fa.w;
            a0[4] = (_Float16)fb.x; a0[5] = (_Float16)fb.y; a0[6] = (_Float16)fb.z; a0[7] = (_Float16)fb.w;
            a1[0] = (_Float16)fc.x; a1[1] = (_Float16)fc.y; a1[2] = (_Float16)fc.z; a1[3] = (_Float16)fc.w;
            a1[4] = (_Float16)fd.x; a1[5] = (_Float16)fd.y; a1[6] = (_Float16)fd.z; a1[7] = (_Float16)fd.w;
        } else {
            a0 = *(const f16x8*)(A16 + aoff0 + k0);
            a1 = *(const f16x8*)(A16 + aoff1 + k0);
        }
#pragma unroll
        for (int q = 0; q < 4; q++) {
            f16x8 bq = *(const f16x8*)(Bsw + (((size_t)(nblk * 4 + q) * KB + kb) * 64 + lane) * 8);
            acc[0][q] = __builtin_amdgcn_mfma_f32_16x16x32_f16(a0, bq, acc[0][q], 0, 0, 0);
            acc[1][q] = __builtin_amdgcn_mfma_f32_16x16x32_f16(a1, bq, acc[1][q], 0, 0, 0);
        }
    }
    // C/D layout: col = lane&15, row = (lane>>4)*4 + reg.  Store gate-interleaved.
#pragma unroll
    for (int mt = 0; mt < 2; mt++)
#pragma unroll
        for (int q = 0; q < 4; q++)
#pragma unroll
            for (int rg = 0; rg < 4; rg++) {
                int row = r0 + mt * 16 + quad * 4 + rg;
                int col = (nblk * 4 + q) * 16 + ln;
                int swz = ((col & 255) << 2) | (col >> 8);
                Gout[(size_t)row * 1024 + swz] = f2h_bits(acc[mt][q][rg]);
            }
}

// ---------------- persistent recurrent kernel: 1 WG per batch element ----------------
// See layout comment at top. Per step:
//   1. one ds_read_b128 per wave pulls this wave's h K-half (256 B) into lanes 0..15
//   2. 64 v_readlane spread it into 64 SGPRs (wave-uniform operands for v_dot2)
//   3. 4 gate-dots over 48 reg uint4 + 16 LDS-tail uint4 (SGPR src0, VGPR weights)
//   4. f32x4 partials to LDS, barrier, add partner wave's (kh^1) partials
//   5. lane-local epilogue (redundant across the wave pair), kh==0 stores h
//   6. barrier
template <int LAYER>
__global__ __launch_bounds__(512, 2) void lstm_rec(const unsigned short* __restrict__ G,
                                                   const unsigned short* __restrict__ RW,
                                                   const unsigned short* __restrict__ LF,
                                                   unsigned short* __restrict__ Y0,
                                                   float* __restrict__ Out)
{
    extern __shared__ char smem[];
    uint4*  lds_w  = (uint4*)smem;                                   // 8192 uint4 = 128 KB
    float4* pb     = (float4*)(smem + 131072);                       // 512 f32x4 = 8 KB
    unsigned short* lds_h0 = (unsigned short*)(smem + 131072 + 8192);// 256 f16
    unsigned short* lds_h1 = lds_h0 + 256;                           // 256 f16

    const int b = blockIdx.x;
    const int tid = threadIdx.x;
    const int wv = tid >> 6, l = tid & 63;
    const int kh = wv & 1;                 // K-half of this wave
    const int ug = wv >> 1;                // unit group
    const int m = ug * 64 + l;             // this lane's unit

    // register-resident weight fragments: rw[g][c] = 4 k-pairs (jp = c*4..c*4+3)
    uint4 rw[4][12];
#pragma unroll
    for (int g = 0; g < 4; ++g)
#pragma unroll
        for (int c = 0; c < 12; ++c)
            rw[g][c] = *(const uint4*)(RW + ((size_t)((g * 12 + c) * 512) + tid) * 8);

    // stage LDS-resident weight tail (jp 48..63)
    {
        const uint4* src = (const uint4*)LF;
        for (int i = tid; i < 8192; i += 512) lds_w[i] = src[i];
    }
    if (tid < 256) lds_h0[tid] = 0;
    float c_state = 0.f, hprev = 0.f;
    __syncthreads();

    // G: gate-interleaved; u16x4 at (row*256 + m) = (f,i,o,g) of unit m
    const u16x4* Gp = (const u16x4*)G;
    const size_t gbase = (size_t)b * 256 + m;
    u16x4 gp = Gp[gbase];                  // t = 0

    for (int t = 0; t < T_STEPS; ++t) {
        // ---- h K-half -> lanes 0..15 (one b128 per wave) ----
        const uint4* hv4 = (const uint4*)((t & 1) ? lds_h1 : lds_h0);
        uint4 hq = hv4[kh * 16 + (l & 15)];

        // next step's G pair (full-step latency cover)
        const int tn = (t + 1 < T_STEPS) ? t + 1 : t;
        u16x4 gpn = Gp[(size_t)tn * 16384 + gbase];

        // deferred store of h_{t-1} (retires during the dot phase)
        if (t && kh == 0) {
            if (LAYER == 0) Y0[((size_t)(t - 1) * 64 + b) * 256 + m] = f2h_bits(hprev);
            else            Out[((size_t)(t - 1) * 64 + b) * 256 + m] = hprev;
        }

        // ---- spread h into 64 wave-uniform SGPRs ----
        unsigned hx = hq.x, hy = hq.y, hz = hq.z, hw = hq.w;
        unsigned sh[64];
#pragma unroll
        for (int q = 0; q < 16; ++q) {
            sh[q * 4 + 0] = __builtin_amdgcn_readlane(hx, q);
            sh[q * 4 + 1] = __builtin_amdgcn_readlane(hy, q);
            sh[q * 4 + 2] = __builtin_amdgcn_readlane(hz, q);
            sh[q * 4 + 3] = __builtin_amdgcn_readlane(hw, q);
        }

        // ---- gate dots over this K-half ----
        float acc[4] = {0.f, 0.f, 0.f, 0.f};
#pragma unroll
        for (int c = 0; c < 12; ++c) {
#pragma unroll
            for (int g = 0; g < 4; ++g) {
                uint4 w = rw[g][c];
                acc[g] = fdot2u(sh[c * 4 + 0], w.x, acc[g]);
                acc[g] = fdot2u(sh[c * 4 + 1], w.y, acc[g]);
                acc[g] = fdot2u(sh[c * 4 + 2], w.z, acc[g]);
                acc[g] = fdot2u(sh[c * 4 + 3], w.w, acc[g]);
            }
        }
#pragma unroll
        for (int cc = 0; cc < 4; ++cc) {
#pragma unroll
            for (int g = 0; g < 4; ++g) {
                uint4 w = lds_w[(g * 4 + cc) * 512 + tid];
                acc[g] = fdot2u(sh[48 + cc * 4 + 0], w.x, acc[g]);
                acc[g] = fdot2u(sh[48 + cc * 4 + 1], w.y, acc[g]);
                acc[g] = fdot2u(sh[48 + cc * 4 + 2], w.z, acc[g]);
                acc[g] = fdot2u(sh[48 + cc * 4 + 3], w.w, acc[g]);
            }
        }

        // ---- combine K-halves via LDS (wave pair wv ^ 1) ----
        float4 pv; pv.x = acc[0]; pv.y = acc[1]; pv.z = acc[2]; pv.w = acc[3];
        pb[tid] = pv;
        __syncthreads();
        float4 pp = pb[tid ^ 64];

        float fg = h2f_scalar(gp[0]) + (acc[0] + pp.x);
        float ig = h2f_scalar(gp[1]) + (acc[1] + pp.y);
        float og = h2f_scalar(gp[2]) + (acc[2] + pp.z);
        float gg = h2f_scalar(gp[3]) + (acc[3] + pp.w);

        float sf = 1.f / (1.f + __expf(-fg));
        float si = 1.f / (1.f + __expf(-ig));
        float so = 1.f / (1.f + __expf(-og));
        float tg = 1.f - 2.f / (1.f + __expf(2.f * gg));
        c_state = sf * c_state + si * tg;
        float tc = 1.f - 2.f / (1.f + __expf(2.f * c_state));
        float h = so * tc;
        hprev = h;

        unsigned short* hn = (t & 1) ? lds_h0 : lds_h1;
        if (kh == 0) hn[m] = f2h_bits(h);
        gp = gpn;
        __syncthreads();
    }
    if (kh == 0) {
        if (LAYER == 0) Y0[((size_t)(T_STEPS - 1) * 64 + b) * 256 + m] = f2h_bits(hprev);
        else            Out[((size_t)(T_STEPS - 1) * 64 + b) * 256 + m] = hprev;
        Out[(size_t)33554432 + (size_t)LAYER * 16384 + (size_t)b * 256 + m] = hprev;          // hn
        Out[(size_t)33554432 + 32768 + (size_t)LAYER * 16384 + (size_t)b * 256 + m] = c_state; // cn
    }
}

// ---------------- launch ----------------
extern "C" void kernel_launch(void* const* d_in, const int* in_sizes, int n_in,
                              void* d_out, int out_size, void* d_ws, size_t ws_size,
                              hipStream_t stream)
{
    const float* x     = (const float*)d_in[0];
    const float* w_ih0 = (const float*)d_in[1];
    const float* w_hh0 = (const float*)d_in[2];
    const float* b0    = (const float*)d_in[3];
    const float* w_ih1 = (const float*)d_in[4];
    const float* w_hh1 = (const float*)d_in[5];
    const float* b1    = (const float*)d_in[6];
    float* out = (float*)d_out;

    if (ws_size < WS_NEED) return;  // cannot run correctly; fail loudly (output stays poisoned)

    char* ws = (char*)d_ws;
    unsigned short* G   = (unsigned short*)(ws + OFF_G);
    unsigned short* Y0  = (unsigned short*)(ws + OFF_Y0);
    unsigned short* RW0 = (unsigned short*)(ws + OFF_RW0);
    unsigned short* RW1 = (unsigned short*)(ws + OFF_RW1);
    unsigned short* LF0 = (unsigned short*)(ws + OFF_LF0);
    unsigned short* LF1 = (unsigned short*)(ws + OFF_LF1);
    unsigned short* BS0 = (unsigned short*)(ws + OFF_BS0);
    unsigned short* BS1 = (unsigned short*)(ws + OFF_BS1);

    (void)hipFuncSetAttribute(reinterpret_cast<const void*>(&lstm_rec<0>),
                              hipFuncAttributeMaxDynamicSharedMemorySize, REC_LDS_BYTES);
    (void)hipFuncSetAttribute(reinterpret_cast<const void*>(&lstm_rec<1>),
                              hipFuncAttributeMaxDynamicSharedMemorySize, REC_LDS_BYTES);

    convert_weights<<<1024, 256, 0, stream>>>(w_ih0, w_hh0, w_ih1, w_hh1,
                                              RW0, RW1, LF0, LF1, BS0, BS1);
    gemm_in<4, 0><<<16384, 256, 0, stream>>>(x, nullptr, BS0, b0, G);
    lstm_rec<0><<<64, 512, REC_LDS_BYTES, stream>>>(G, RW0, LF0, Y0, out);
    gemm_in<8, 1><<<16384, 256, 0, stream>>>(nullptr, Y0, BS1, b1, G);
    lstm_rec<1><<<64, 512, REC_LDS_BYTES, stream>>>(G, RW1, LF1, Y0, out);
}